// Round 12
// baseline (174.636 us; speedup 1.0000x reference)
//
#include <hip/hip_runtime.h>
#include <math.h>

using short8 = __attribute__((ext_vector_type(8))) short;   // 8 bf16 in 4 VGPRs
using f32x4  = __attribute__((ext_vector_type(4))) float;
using us4    = __attribute__((ext_vector_type(4))) unsigned short;
typedef unsigned short ushort_t;

#define MFMA16(a,b,c) __builtin_amdgcn_mfma_f32_16x16x32_bf16((a),(b),(c),0,0,0)

#define BB 2
#define TT 2048
#define CC 512
#define HH 8
#define DD 64
#define N3 1536
#define NCH 32   // chunks of 64 along T

__device__ __forceinline__ float bf2f(ushort_t u){ unsigned int x=((unsigned int)u)<<16; return __builtin_bit_cast(float,x); }
__device__ __forceinline__ ushort_t f2bf(float f){ unsigned int u=__builtin_bit_cast(unsigned int,f); u += 0x7FFFu + ((u>>16)&1u); return (ushort_t)(u>>16); }
__device__ __forceinline__ float elu1(float v){ return v > 0.f ? v + 1.f : expf(v); }

// ---------- K1: qkv = x @ Wqkv + b (reads f32 x/W directly; prep fused away) ----------
// grid (24, 32): x = n-block (64 cols = one head of one third), y = m-block (128 rows)
__global__ __launch_bounds__(256) void gemm_qkv(const float* __restrict__ X, const float* __restrict__ W,
    const float* __restrict__ bias, const float* __restrict__ amask,
    ushort_t* __restrict__ phiQ, ushort_t* __restrict__ phiK,
    ushort_t* __restrict__ kTc, ushort_t* __restrict__ vTc)
{
  __shared__ __align__(16) ushort_t smem[128*72 + 64*72];
  __shared__ float ml[128];
  ushort_t (*lA)[72] = (ushort_t(*)[72])smem;
  ushort_t (*lB)[72] = (ushort_t(*)[72])(smem + 128*72);
  const int tid = threadIdx.x;
  const int lane = tid & 63, wid = tid >> 6;
  const int g = lane >> 4, lr = lane & 15;
  const int bx = blockIdx.x, bm = blockIdx.y * 128;
  const int bn = bx * 64;
  const int wm = (wid >> 1) * 64, wn = (wid & 1) * 32;
  const int b0 = bm >> 11;
  // mask diagonal -> LDS (one element per output row)
  if (tid < 128) {
    int t = (bm + tid) & 2047;
    ml[tid] = amask[((size_t)b0*TT + t)*TT + t];
  }
  f32x4 acc[4][2] = {};

  // prologue: stage K-tile 0 (cast f32->bf16; B transposed)
  {
    #pragma unroll
    for (int it=0; it<8; ++it) {
      int fl = tid + it*256;
      int row = fl >> 4, seg = fl & 15;
      f32x4 v = *(const f32x4*)&X[(size_t)(bm+row)*CC + seg*4];
      us4 o = { f2bf(v[0]), f2bf(v[1]), f2bf(v[2]), f2bf(v[3]) };
      *(us4*)&lA[row][seg*4] = o;
    }
    #pragma unroll
    for (int it=0; it<4; ++it) {
      int fl = tid + it*256;
      int krow = fl >> 4, seg = fl & 15;
      f32x4 v = *(const f32x4*)&W[(size_t)krow*N3 + bn + seg*4];
      lB[seg*4+0][krow] = f2bf(v[0]);
      lB[seg*4+1][krow] = f2bf(v[1]);
      lB[seg*4+2][krow] = f2bf(v[2]);
      lB[seg*4+3][krow] = f2bf(v[3]);
    }
  }
  __syncthreads();

  #pragma unroll
  for (int t = 0; t < 8; ++t) {
    f32x4 nA[8], nB[4];
    if (t < 7) {
      int k0 = (t+1)*64;
      #pragma unroll
      for (int it=0; it<8; ++it) {
        int fl = tid + it*256;
        int row = fl >> 4, seg = fl & 15;
        nA[it] = *(const f32x4*)&X[(size_t)(bm+row)*CC + k0 + seg*4];
      }
      #pragma unroll
      for (int it=0; it<4; ++it) {
        int fl = tid + it*256;
        int krow = fl >> 4, seg = fl & 15;
        nB[it] = *(const f32x4*)&W[(size_t)(k0+krow)*N3 + bn + seg*4];
      }
    }
    short8 af[4][2], bf[2][2];
    #pragma unroll
    for (int mf=0; mf<4; ++mf)
      #pragma unroll
      for (int kk=0; kk<2; ++kk) af[mf][kk] = *(const short8*)&lA[wm + mf*16 + lr][kk*32 + g*8];
    #pragma unroll
    for (int nf=0; nf<2; ++nf)
      #pragma unroll
      for (int kk=0; kk<2; ++kk) bf[nf][kk] = *(const short8*)&lB[wn + nf*16 + lr][kk*32 + g*8];
    #pragma unroll
    for (int kk=0; kk<2; ++kk)
      #pragma unroll
      for (int mf=0; mf<4; ++mf)
        #pragma unroll
        for (int nf=0; nf<2; ++nf)
          acc[mf][nf] = MFMA16(af[mf][kk], bf[nf][kk], acc[mf][nf]);
    __syncthreads();
    if (t < 7) {
      #pragma unroll
      for (int it=0; it<8; ++it) {
        int fl = tid + it*256;
        int row = fl >> 4, seg = fl & 15;
        us4 o = { f2bf(nA[it][0]), f2bf(nA[it][1]), f2bf(nA[it][2]), f2bf(nA[it][3]) };
        *(us4*)&lA[row][seg*4] = o;
      }
      #pragma unroll
      for (int it=0; it<4; ++it) {
        int fl = tid + it*256;
        int krow = fl >> 4, seg = fl & 15;
        lB[seg*4+0][krow] = f2bf(nB[it][0]);
        lB[seg*4+1][krow] = f2bf(nB[it][1]);
        lB[seg*4+2][krow] = f2bf(nB[it][2]);
        lB[seg*4+3][krow] = f2bf(nB[it][3]);
      }
      __syncthreads();
    }
  }

  // epilogue: phiQ/phiK direct; kTc/vTc via LDS transpose
  const int third = bx >> 3, h = bx & 7;
  const size_t bh = (size_t)(b0*HH + h);
  ushort_t (*ldsT)[136] = (ushort_t(*)[136])smem;
  #pragma unroll
  for (int mf=0; mf<4; ++mf) {
    #pragma unroll
    for (int nf=0; nf<2; ++nf) {
      int d = wn + nf*16 + lr;
      float bs = bias[third*512 + h*64 + d];
      #pragma unroll
      for (int r=0; r<4; ++r) {
        int tl = wm + mf*16 + g*4 + r;
        int tg = (bm + tl) & 2047;
        float v = acc[mf][nf][r] + bs;
        if (third == 0) {
          phiQ[(bh*TT + tg)*DD + d] = f2bf(elu1(v));
        } else if (third == 1) {
          ushort_t e = f2bf(elu1(v) * ml[tl]);
          phiK[(bh*TT + tg)*DD + d] = e;
          ldsT[d][tl] = e;
        } else {
          ldsT[d][tl] = f2bf(v * ml[tl]);
        }
      }
    }
  }
  if (third >= 1) {
    __syncthreads();
    ushort_t* dst = (third == 1) ? kTc : vTc;
    int d = tid >> 2, q = tid & 3;
    int cl = q >> 1, tl0 = (q & 1) * 32;
    int c0 = ((bm & 2047) >> 6) + cl;
    size_t obase = ((bh*NCH + c0)*DD + d)*64 + tl0;
    #pragma unroll
    for (int j=0; j<4; ++j)
      *(short8*)&dst[obase + j*8] = *(const short8*)&ldsT[d][cl*64 + tl0 + j*8];
  }
}

// ---------- K2: fused chunk-state + exclusive scan, state lives in MFMA accumulators ----------
// grid 64 = (bh*4 + jb); 4 waves, wave ib owns i-block mf=ib. sChunk never materialized.
__global__ __launch_bounds__(256) void state_scan(const ushort_t* __restrict__ kTc,
                                                  const ushort_t* __restrict__ vTc,
                                                  ushort_t* __restrict__ sPrev)
{
  int bh = blockIdx.x >> 2, jb = blockIdx.x & 3;
  int ib = threadIdx.x >> 6;
  int lane = threadIdx.x & 63, g = lane >> 4, lr = lane & 15;
  f32x4 acc  = {0.f,0.f,0.f,0.f};   // S[j=jb*16+lr][i=ib*16+g*4+r] running sum
  f32x4 accO = {0.f,0.f,0.f,0.f};   // ones-row (j=64), jb==0 blocks only
  short8 onesf;
  {
    short ov = (lr == 0) ? (short)0x3F80 : (short)0;
    #pragma unroll
    for (int j=0;j<8;++j) onesf[j] = ov;
  }
  for (int c = 0; c < NCH; ++c) {
    size_t cid = (size_t)bh*NCH + c;
    size_t base = cid * (DD*64);
    short8 af[2], bfr[2];
    #pragma unroll
    for (int kf=0; kf<2; ++kf) {
      af[kf]  = *(const short8*)&kTc[base + (size_t)(ib*16+lr)*64 + kf*32 + g*8];
      bfr[kf] = *(const short8*)&vTc[base + (size_t)(jb*16+lr)*64 + kf*32 + g*8];
    }
    // store exclusive prefix BEFORE accumulating chunk c
    {
      us4 o = { f2bf(acc[0]), f2bf(acc[1]), f2bf(acc[2]), f2bf(acc[3]) };
      *(us4*)&sPrev[cid*5120 + (size_t)(jb*16+lr)*64 + ib*16 + g*4] = o;
    }
    if (jb == 0 && lr == 0) {
      us4 o = { f2bf(accO[0]), f2bf(accO[1]), f2bf(accO[2]), f2bf(accO[3]) };
      *(us4*)&sPrev[cid*5120 + (size_t)64*64 + ib*16 + g*4] = o;
    }
    #pragma unroll
    for (int kf=0; kf<2; ++kf) acc = MFMA16(af[kf], bfr[kf], acc);
    if (jb == 0) {
      #pragma unroll
      for (int kf=0; kf<2; ++kf) accO = MFMA16(af[kf], onesf, accO);
    }
  }
}

// ---------- K3: per-chunk output, 2048 one-wave blocks (16 q-rows each) ----------
__global__ __launch_bounds__(64) void chunk_out(const ushort_t* __restrict__ phiQ,
    const ushort_t* __restrict__ phiK, const ushort_t* __restrict__ vTc,
    const ushort_t* __restrict__ sPrev, ushort_t* __restrict__ ya)
{
  __shared__ __align__(16) ushort_t P[16][72];
  int bid = blockIdx.x;                  // ((bh*32 + c)*4 + q)
  int q = bid & 3, cid = bid >> 2;
  int bh = cid >> 5, c = cid & 31;
  int lane = threadIdx.x, g = lane >> 4, lr = lane & 15;
  int t0 = c * 64, tq = t0 + q*16;
  size_t qbase = (size_t)bh*TT;
  size_t vbase = (size_t)cid * (DD*64);
  short8 qf[2];
  #pragma unroll
  for (int kf=0;kf<2;++kf)
    qf[kf] = *(const short8*)&phiQ[(qbase + tq + lr)*DD + kf*32 + g*8];
  // QK^T (16 x 64)
  f32x4 accs[4] = {};
  #pragma unroll
  for (int nf=0;nf<4;++nf)
    #pragma unroll
    for (int kf=0;kf<2;++kf) {
      short8 bk = *(const short8*)&phiK[(qbase + t0 + nf*16 + lr)*DD + kf*32 + g*8];
      accs[nf] = MFMA16(qf[kf], bk, accs[nf]);
    }
  // Q @ S_prev (cols 0..63 numerator; row 64 = denominator prefix, lr==0 only)
  f32x4 accn[5] = {};
  size_t sbase = (size_t)cid * 5120;
  #pragma unroll
  for (int nf=0;nf<4;++nf)
    #pragma unroll
    for (int kf=0;kf<2;++kf) {
      short8 bs = *(const short8*)&sPrev[sbase + (size_t)(nf*16+lr)*64 + kf*32 + g*8];
      accn[nf] = MFMA16(qf[kf], bs, accn[nf]);
    }
  #pragma unroll
  for (int kf=0;kf<2;++kf) {
    short8 bs = {0,0,0,0,0,0,0,0};
    if (lr == 0) bs = *(const short8*)&sPrev[sbase + (size_t)64*64 + kf*32 + g*8];
    accn[4] = MFMA16(qf[kf], bs, accn[4]);
  }
  // masked P -> LDS (bf16)
  #pragma unroll
  for (int nf=0;nf<4;++nf)
    #pragma unroll
    for (int r=0;r<4;++r) {
      int tl = g*4 + r, s = nf*16 + lr;
      P[tl][s] = f2bf((s <= q*16 + tl) ? accs[nf][r] : 0.f);
    }
  __syncthreads();
  short8 pf[2];
  #pragma unroll
  for (int kf=0;kf<2;++kf)
    pf[kf] = *(const short8*)&P[lr][kf*32 + g*8];
  // P @ V_aug (ones col -> rowsum(P) joins accn[4])
  short8 onesf;
  {
    short ov = (lr == 0) ? (short)0x3F80 : (short)0;
    #pragma unroll
    for (int j=0;j<8;++j) onesf[j] = ov;
  }
  #pragma unroll
  for (int nf=0;nf<5;++nf)
    #pragma unroll
    for (int kf=0;kf<2;++kf) {
      short8 vf = (nf < 4) ? *(const short8*)&vTc[vbase + (size_t)(nf*16+lr)*64 + kf*32 + g*8]
                           : onesf;
      accn[nf] = MFMA16(pf[kf], vf, accn[nf]);
    }
  float invb[4];
  #pragma unroll
  for (int r=0;r<4;++r) {
    float iv = 1.0f / fmaxf(accn[4][r], 1e-8f);
    invb[r] = __shfl(iv, lane & 48);
  }
  int b = bh >> 3, h = bh & 7;
  #pragma unroll
  for (int nf=0;nf<4;++nf)
    #pragma unroll
    for (int r=0;r<4;++r) {
      int t = tq + g*4 + r;
      int col = h*64 + nf*16 + lr;
      ya[((size_t)b*TT + t)*CC + col] = f2bf(accn[nf][r] * invb[r]);
    }
}

// ---------- K4: out = ya @ c_proj + bias (reads f32 Pw directly, transposed staging) ----------
__global__ __launch_bounds__(256) void gemm_proj(const ushort_t* __restrict__ A, const float* __restrict__ Pw,
                                                 const float* __restrict__ bias, float* __restrict__ out)
{
  __shared__ __align__(16) ushort_t lA[32][72];
  __shared__ __align__(16) ushort_t lB[64][72];
  const int tid = threadIdx.x;
  const int lane = tid & 63, wid = tid >> 6;
  const int g = lane >> 4, lr = lane & 15;
  const int bm = blockIdx.y * 32, bn = blockIdx.x * 64;
  const int wm = (wid >> 1) * 16, wn = (wid & 1) * 32;
  f32x4 acc[2] = {};
  {
    int fl = tid;
    short8 nA = *(const short8*)&A[(size_t)(bm + (fl>>3))*CC + (fl&7)*8];
    *(short8*)&lA[fl>>3][(fl&7)*8] = nA;
    #pragma unroll
    for (int it=0; it<4; ++it) {
      int f2 = tid + it*256;
      int krow = f2 >> 4, seg = f2 & 15;
      f32x4 v = *(const f32x4*)&Pw[(size_t)krow*CC + bn + seg*4];
      lB[seg*4+0][krow] = f2bf(v[0]);
      lB[seg*4+1][krow] = f2bf(v[1]);
      lB[seg*4+2][krow] = f2bf(v[2]);
      lB[seg*4+3][krow] = f2bf(v[3]);
    }
  }
  __syncthreads();
  #pragma unroll
  for (int t = 0; t < 8; ++t) {
    short8 nA;
    f32x4 nB[4];
    if (t < 7) {
      int k0 = (t+1)*64;
      { int fl = tid; nA = *(const short8*)&A[(size_t)(bm + (fl>>3))*CC + k0 + (fl&7)*8]; }
      #pragma unroll
      for (int it=0; it<4; ++it) {
        int f2 = tid + it*256;
        int krow = f2 >> 4, seg = f2 & 15;
        nB[it] = *(const f32x4*)&Pw[(size_t)(k0+krow)*CC + bn + seg*4];
      }
    }
    short8 af[2], bf[2][2];
    #pragma unroll
    for (int kk=0; kk<2; ++kk) af[kk] = *(const short8*)&lA[wm + lr][kk*32 + g*8];
    #pragma unroll
    for (int nf=0; nf<2; ++nf)
      #pragma unroll
      for (int kk=0; kk<2; ++kk) bf[nf][kk] = *(const short8*)&lB[wn + nf*16 + lr][kk*32 + g*8];
    #pragma unroll
    for (int kk=0; kk<2; ++kk)
      #pragma unroll
      for (int nf=0; nf<2; ++nf)
        acc[nf] = MFMA16(af[kk], bf[nf][kk], acc[nf]);
    __syncthreads();
    if (t < 7) {
      { int fl = tid; *(short8*)&lA[fl>>3][(fl&7)*8] = nA; }
      #pragma unroll
      for (int it=0; it<4; ++it) {
        int f2 = tid + it*256;
        int krow = f2 >> 4, seg = f2 & 15;
        lB[seg*4+0][krow] = f2bf(nB[it][0]);
        lB[seg*4+1][krow] = f2bf(nB[it][1]);
        lB[seg*4+2][krow] = f2bf(nB[it][2]);
        lB[seg*4+3][krow] = f2bf(nB[it][3]);
      }
      __syncthreads();
    }
  }
  int m0 = bm + wm + g*4;
  #pragma unroll
  for (int nf=0; nf<2; ++nf) {
    int n = bn + wn + nf*16 + lr;
    #pragma unroll
    for (int r=0; r<4; ++r)
      out[(size_t)(m0 + r)*CC + n] = acc[nf][r] + bias[n];
  }
}

extern "C" void kernel_launch(void* const* d_in, const int* in_sizes, int n_in,
                              void* d_out, int out_size, void* d_ws, size_t ws_size,
                              hipStream_t stream)
{
  const float* x     = (const float*)d_in[0];
  const float* amask = (const float*)d_in[1];
  const float* wqkv  = (const float*)d_in[2];
  const float* bqkv  = (const float*)d_in[3];
  const float* wproj = (const float*)d_in[4];
  const float* bproj = (const float*)d_in[5];
  float* out = (float*)d_out;
  char* ws = (char*)d_ws;

  ushort_t* phiQ  = (ushort_t*)(ws + 0);          // [bh][t][d] bf16    (4 MB)
  ushort_t* phiK  = (ushort_t*)(ws + 4194304);    // [bh][t][d] bf16    (4 MB)
  ushort_t* kTc   = (ushort_t*)(ws + 8388608);    // [bh][c][d][64]     (4 MB)
  ushort_t* vTc   = (ushort_t*)(ws + 12582912);   // [bh][c][d][64]     (4 MB)
  ushort_t* ya    = (ushort_t*)(ws + 16777216);   // 4096x512 bf16      (4 MB)
  ushort_t* sPrev = (ushort_t*)(ws + 20971520);   // 512 x 80x64 bf16   (5.25 MB)

  gemm_qkv<<<dim3(24,32), dim3(256), 0, stream>>>(x, wqkv, bqkv, amask, phiQ, phiK, kTc, vTc);
  state_scan<<<dim3(64), dim3(256), 0, stream>>>(kTc, vTc, sPrev);
  chunk_out<<<dim3(2048), dim3(64), 0, stream>>>(phiQ, phiK, vTc, sPrev, ya);
  gemm_proj<<<dim3(8,128), dim3(256), 0, stream>>>(ya, wproj, bproj, out);
}